// Round 20
// baseline (34350.931 us; speedup 1.0000x reference)
//
#include <hip/hip_runtime.h>

// ---------------------------------------------------------------------------
// OmniAnomaly forward, round 20: chain-split + composed linear heads.
// d-layer is LINEAR -> fold Wd into heads: mu = e@(Wmu Wd_e)^T + z@(Wmu Wd_z)^T + c.
// Roles (grid 160): QG 64 (Q-GRU, 8 slabs x 8 col-pieces, 32 rows/slab),
// QH 16 (e-head + z-chain + flows, z in LDS, 16 rows each), PG 64 (P-GRU),
// PH 16 (P output head, eager). Chains pipeline with slack; critical path ==
// Q-GRU recurrence (1 hop/step). Proven pieces: r18 GRU/stage/flags,
// sc0sc1 writes + cached unique-address reads, r10 flows.
// B=256, W=128, IN=128, H=1024, Z=128, D=1024, OUT=128, K=3 flows
// ---------------------------------------------------------------------------

typedef __bf16 bf16;
typedef __bf16 bf16x8 __attribute__((ext_vector_type(8)));
typedef float  f32x4  __attribute__((ext_vector_type(4)));
typedef unsigned u32;

static constexpr int CB   = 256;
static constexpr int CW   = 128;
static constexpr int CIN  = 128;
static constexpr int CH   = 1024;
static constexpr int CZ   = 128;
static constexpr int CD   = 1024;
static constexpr int COUT = 128;

static constexpr int APITCH = 1160;                  // 1152 + 8 pad
static constexpr int SMEM_BYTES = 32 * APITCH * 2;   // 74240 (QG/PG 32-row abuf)
static constexpr int ABUF16 = 16 * APITCH * 2;       // 37120 (QH/PH abuf)

#define DEV static __device__ __forceinline__

DEV float sigmoidf_(float x) { return 1.0f / (1.0f + expf(-x)); }
DEV float softplusf_(float x) { return x > 20.0f ? x : log1pf(expf(x)); }
DEV bf16x8 ldfrag(const bf16* p) { return *reinterpret_cast<const bf16x8*>(p); }

#define MFMA(a, b, c) __builtin_amdgcn_mfma_f32_16x16x32_bf16((a), (b), (c), 0, 0, 0)

DEV void std4(void* p, u32 v) {
    asm volatile("global_store_dword %0, %1, off sc0 sc1" :: "v"(p), "v"(v) : "memory");
}
DEV u32 pk2(float a, float b) {
    union { bf16 h[2]; u32 u; } r;
    r.h[0] = (bf16)a; r.h[1] = (bf16)b;
    return r.u;
}

struct Prm {
    const float *eps_q, *eps_p;
    const float *bih_q, *bhh_q, *bih_p, *bhh_p;
    const float *Wp, *bp, *up, *Wlg, *blg;
    const bf16 *x_b, *Wih_qb, *Whh_qb, *Wih_pb, *Whh_pb;
    const bf16 *Amu_q, *Asig_q, *Amu_p, *Asig_p;     // composed [128][1024] bf16
    const float *Bmu_q, *Bsig_q;                     // composed [128][128] f32
    const float *cmu_q, *csig_q, *cmu_p, *csig_p;    // composed [128] f32
    float *e_f, *d_f;       // [2][CB][CH] fp32 masters (WG-private patches)
    bf16 *e_h, *d_h;        // [CW+1][CB][CH]
    bf16 *ztlg;             // [CW][CB][CZ]
    u32 *qg, *qh, *pg;      // flags (16-u32 spacing)
    float *out_o, *out_mu, *out_lv;
};

// ---- flag helpers ----
DEV void post_flag(u32* f, int idx, u32 k)
{
    asm volatile("s_waitcnt vmcnt(0)" ::: "memory");
    __syncthreads();
    if (threadIdx.x == 0)
        __hip_atomic_store(&f[idx * 16], k, __ATOMIC_RELAXED, __HIP_MEMORY_SCOPE_AGENT);
}
DEV void wait8(const u32* f, int base, int k)
{
    if (k > 0 && threadIdx.x < 8) {
        while ((int)__hip_atomic_load(&f[(base + threadIdx.x) * 16], __ATOMIC_RELAXED,
                                      __HIP_MEMORY_SCOPE_AGENT) < k)
            __builtin_amdgcn_s_sleep(1);
    }
    __syncthreads();
}
DEV void waitPG(const u32* qh, const u32* pg, int s, int t)
{
    if (threadIdx.x < 2) {
        while ((int)__hip_atomic_load(&qh[(2 * s + threadIdx.x) * 16], __ATOMIC_RELAXED,
                                      __HIP_MEMORY_SCOPE_AGENT) < t + 1)
            __builtin_amdgcn_s_sleep(1);
    } else if (threadIdx.x < 10 && t > 0) {
        const int j = (int)threadIdx.x - 2;
        while ((int)__hip_atomic_load(&pg[(s * 8 + j) * 16], __ATOMIC_RELAXED,
                                      __HIP_MEMORY_SCOPE_AGENT) < t)
            __builtin_amdgcn_s_sleep(1);
    }
    __syncthreads();
}

// ---------------------------------------------------------------------------
__global__ void k_cvt(const float* __restrict__ src, bf16* __restrict__ dst, int n)
{
    int i = (blockIdx.x * blockDim.x + threadIdx.x) * 4;
    if (i < n) {
        float4 v = *reinterpret_cast<const float4*>(src + i);
        *reinterpret_cast<u32*>(dst + i)     = pk2(v.x, v.y);
        *reinterpret_cast<u32*>(dst + i + 2) = pk2(v.z, v.w);
    }
}

// ---------------------------------------------------------------------------
// Compose: A[i][j] = sum_k M[i][k]*Wd[k][offA+j] (j<1024, bf16 out)
//          B[i][j] = sum_k M[i][k]*Wd[k][j]      (j<NB, f32 out; NB may be 0)
//          c[i]    = sum_k M[i][k]*bd[k] + bias[i]
// grid 128 (i), block 256. Wd row-major [1024][ldWd].
// ---------------------------------------------------------------------------
__global__ void k_comp(const float* __restrict__ M, const float* __restrict__ Wd,
                       int ldWd, int offA, const float* __restrict__ bd,
                       const float* __restrict__ bias,
                       bf16* __restrict__ A, float* __restrict__ B, int NB,
                       float* __restrict__ cvec)
{
    const int i = blockIdx.x;
    const int tid = threadIdx.x;
    const float* m = M + (long)i * CD;
    float accA[4] = {0.f, 0.f, 0.f, 0.f};
    float accB = 0.f, accC = 0.f;
    for (int k = 0; k < CD; ++k) {
        const float w = m[k];
        const float* wr = Wd + (long)k * ldWd;
#pragma unroll
        for (int j = 0; j < 4; ++j)
            accA[j] += w * wr[offA + tid + j * 256];
        if (NB && tid < NB) accB += w * wr[tid];
        if (tid == 0) accC += w * bd[k];
    }
#pragma unroll
    for (int j = 0; j < 4; ++j)
        A[(long)i * CD + tid + j * 256] = (bf16)accA[j];
    if (NB && tid < NB) B[(long)i * NB + tid] = accB;
    if (tid == 0) cvec[i] = accC + bias[i];
}

// ---------------------------------------------------------------------------
// Staging (cached unique-address reads; sources written sc0sc1 by producers).
// ---------------------------------------------------------------------------
DEV void stage32(bf16* abuf, int tid, int r0,
                 const bf16* head, long hs, const bf16* body)
{
#pragma unroll
    for (int j = 0; j < 8; ++j) {
        const int idx = tid + j * 512;
        const int row = idx >> 7;
        const int k = (idx & 127) * 8;
        *reinterpret_cast<bf16x8*>(abuf + (long)row * APITCH + CIN + k) =
            ldfrag(body + (long)(r0 + row) * CH + k);
    }
    {
        const int row = tid >> 4;
        const int k = (tid & 15) * 8;
        *reinterpret_cast<bf16x8*>(abuf + (long)row * APITCH + k) =
            ldfrag(head + (long)(r0 + row) * hs + k);
    }
    __syncthreads();
}
DEV void stage16(bf16* abuf, int tid, int r0, const bf16* body)
{
#pragma unroll
    for (int j = 0; j < 4; ++j) {
        const int idx = tid + j * 512;
        const int row = idx >> 7;
        const int k = (idx & 127) * 8;
        *reinterpret_cast<bf16x8*>(abuf + (long)row * APITCH + k) =
            ldfrag(body + (long)(r0 + row) * CH + k);
    }
    __syncthreads();
}

// ---------------------------------------------------------------------------
// GRU over 32 rows x 128 cols (2 A-frags/wave, rotating weight prefetch).
// ---------------------------------------------------------------------------
DEV void gru32(const bf16* abuf, int r0, int n0, int lane, int wave,
               const bf16* __restrict__ Wih, const bf16* __restrict__ Whh,
               const float* __restrict__ bih, const float* __restrict__ bhh,
               const float* __restrict__ Efin,
               float* __restrict__ Efo, bf16* __restrict__ Ebo)
{
    const int lr = lane & 15, lkE = (lane >> 4) * 8;
    const int c = n0 + wave * 16 + lr;
    const bf16* a0p = abuf + (long)lr * APITCH;
    const bf16* a1p = abuf + (long)(16 + lr) * APITCH;

    f32x4 acc[4][2] = {};
    {   // input segment K=128
        bf16x8 wv[4][3];
#pragma unroll
        for (int j = 0; j < 4; ++j)
#pragma unroll
            for (int g = 0; g < 3; ++g)
                wv[j][g] = ldfrag(Wih + ((long)g * CH + c) * CIN + j * 32 + lkE);
#pragma unroll
        for (int j = 0; j < 4; ++j) {
            bf16x8 a0 = *reinterpret_cast<const bf16x8*>(a0p + j * 32 + lkE);
            bf16x8 a1 = *reinterpret_cast<const bf16x8*>(a1p + j * 32 + lkE);
#pragma unroll
            for (int g = 0; g < 3; ++g) {
                const int grp = (g == 2) ? 2 : g;
                acc[grp][0] = MFMA(a0, wv[j][g], acc[grp][0]);
                acc[grp][1] = MFMA(a1, wv[j][g], acc[grp][1]);
            }
        }
    }
    {   // hidden segment K=1024, 4-deep x3 rotating prefetch
        const bf16* wp0 = Whh + ((long)0 * CH + c) * CH + lkE;
        const bf16* wp1 = Whh + ((long)1 * CH + c) * CH + lkE;
        const bf16* wp2 = Whh + ((long)2 * CH + c) * CH + lkE;
        bf16x8 wv[4][3];
#pragma unroll
        for (int j = 0; j < 4; ++j) {
            wv[j][0] = ldfrag(wp0 + j * 32);
            wv[j][1] = ldfrag(wp1 + j * 32);
            wv[j][2] = ldfrag(wp2 + j * 32);
        }
#pragma unroll
        for (int kb = 0; kb < 32; ++kb) {
            const int sl = kb & 3;
            bf16x8 a0 = *reinterpret_cast<const bf16x8*>(a0p + CIN + kb * 32 + lkE);
            bf16x8 a1 = *reinterpret_cast<const bf16x8*>(a1p + CIN + kb * 32 + lkE);
            acc[0][0] = MFMA(a0, wv[sl][0], acc[0][0]);
            acc[0][1] = MFMA(a1, wv[sl][0], acc[0][1]);
            acc[1][0] = MFMA(a0, wv[sl][1], acc[1][0]);
            acc[1][1] = MFMA(a1, wv[sl][1], acc[1][1]);
            acc[3][0] = MFMA(a0, wv[sl][2], acc[3][0]);
            acc[3][1] = MFMA(a1, wv[sl][2], acc[3][1]);
            if (kb < 28) {
                wv[sl][0] = ldfrag(wp0 + (kb + 4) * 32);
                wv[sl][1] = ldfrag(wp1 + (kb + 4) * 32);
                wv[sl][2] = ldfrag(wp2 + (kb + 4) * 32);
            }
        }
    }

    const float b0r = bih[c] + bhh[c];
    const float b0z = bih[CH + c] + bhh[CH + c];
    const float bin = bih[2 * CH + c];
    const float bhn = bhh[2 * CH + c];
#pragma unroll
    for (int f = 0; f < 2; ++f) {
        const int rbase = r0 + f * 16 + (lane >> 4) * 4;
#pragma unroll
        for (int i = 0; i < 4; ++i) {
            const int row = rbase + i;
            float r = sigmoidf_(acc[0][f][i] + b0r);
            float u = sigmoidf_(acc[1][f][i] + b0z);
            float n = tanhf(acc[2][f][i] + bin + r * (acc[3][f][i] + bhn));
            float en = (1.0f - u) * n + u * Efin[(long)row * CH + c];
            Efo[(long)row * CH + c] = en;
            float vB = __shfl_xor(en, 1);
            if (!(lane & 1))
                std4(Ebo + (long)row * CH + c, pk2(en, vB));
        }
    }
}

// ---------------------------------------------------------------------------
// Head GEMM: 16 rows x 256 out-cols (mu 0-127, sig 128-255) from abuf (K=1024).
// Waves 0-3 -> mu, 4-7 -> sig; 2 col-frags each. Results -> muE/sigE LDS.
// ---------------------------------------------------------------------------
DEV void ehead(const bf16* abuf, int lane, int wave,
               const bf16* __restrict__ Amu, const bf16* __restrict__ Asig,
               float* muE, float* sigE)
{
    const int lr = lane & 15, lkE = (lane >> 4) * 8;
    const bf16* Wh = (wave < 4) ? Amu : Asig;
    float* outE = (wave < 4) ? muE : sigE;
    const int cb = (wave & 3) * 32;
    const bf16* w0 = Wh + (long)(cb + lr) * CD + lkE;
    const bf16* w1 = Wh + (long)(cb + 16 + lr) * CD + lkE;
    const bf16* arow = abuf + (long)lr * APITCH;

    f32x4 acc[2] = {};
    bf16x8 wv0[4], wv1[4];
#pragma unroll
    for (int j = 0; j < 4; ++j) { wv0[j] = ldfrag(w0 + j * 32); wv1[j] = ldfrag(w1 + j * 32); }
#pragma unroll
    for (int kb = 0; kb < 32; ++kb) {
        const int sl = kb & 3;
        bf16x8 a = *reinterpret_cast<const bf16x8*>(arow + kb * 32 + lkE);
        acc[0] = MFMA(a, wv0[sl], acc[0]);
        acc[1] = MFMA(a, wv1[sl], acc[1]);
        if (kb < 28) { wv0[sl] = ldfrag(w0 + (kb + 4) * 32); wv1[sl] = ldfrag(w1 + (kb + 4) * 32); }
    }
#pragma unroll
    for (int f = 0; f < 2; ++f)
#pragma unroll
        for (int i = 0; i < 4; ++i) {
            const int row = (lane >> 4) * 4 + i;
            const int col = cb + f * 16 + lr;
            outE[row * CZ + col] = acc[f][i];
        }
}

// ---------------------------------------------------------------------------
// QH z-phase: combine heads + reparam + flows + Wlg; z persistent in zbuf.
// thread: r = tid>>5 (16 rows), c0 = (tid&31)*4.
// ---------------------------------------------------------------------------
DEV void zphase(const Prm& p, int h, int t, int tid,
                const float* muE, const float* sigE, float* zbuf)
{
    const int r = tid >> 5, c0 = (tid & 31) * 4;
    const int row = h * 16 + r;
    float dm[4] = {0.f,0.f,0.f,0.f}, ds[4] = {0.f,0.f,0.f,0.f};
    for (int k = 0; k < CZ; k += 4) {
        float4 z4 = *reinterpret_cast<const float4*>(&zbuf[r * CZ + k]);
#pragma unroll
        for (int j = 0; j < 4; ++j) {
            float4 bm = *reinterpret_cast<const float4*>(&p.Bmu_q[(long)(c0 + j) * CZ + k]);
            float4 bs = *reinterpret_cast<const float4*>(&p.Bsig_q[(long)(c0 + j) * CZ + k]);
            dm[j] += z4.x * bm.x + z4.y * bm.y + z4.z * bm.z + z4.w * bm.w;
            ds[j] += z4.x * bs.x + z4.y * bs.y + z4.z * bs.z + z4.w * bs.w;
        }
    }
    float zn[4];
#pragma unroll
    for (int j = 0; j < 4; ++j) {
        const int col = c0 + j;
        float mu = muE[r * CZ + col] + dm[j] + p.cmu_q[col];
        float lv = softplusf_(sigE[r * CZ + col] + ds[j] + p.csig_q[col]);
        p.out_mu[(size_t)row * CW * CZ + (size_t)t * CZ + col] = mu;
        p.out_lv[(size_t)row * CW * CZ + (size_t)t * CZ + col] = lv;
        zn[j] = mu + expf(0.5f * lv) * p.eps_q[(size_t)row * CW * CZ + (size_t)t * CZ + col];
    }
    __syncthreads();
#pragma unroll
    for (int j = 0; j < 4; ++j) zbuf[r * CZ + c0 + j] = zn[j];
    __syncthreads();

    // planar flows x3 (fp32, in-LDS)
    for (int kf = 0; kf < 3; ++kf) {
        float s[4] = { p.bp[kf * CZ + c0], p.bp[kf * CZ + c0 + 1],
                       p.bp[kf * CZ + c0 + 2], p.bp[kf * CZ + c0 + 3] };
        const float* w0 = p.Wp + ((long)kf * CZ + c0) * CZ;
        for (int k = 0; k < CZ; k += 4) {
            float4 z4 = *reinterpret_cast<const float4*>(&zbuf[r * CZ + k]);
#pragma unroll
            for (int j = 0; j < 4; ++j) {
                float4 w = *reinterpret_cast<const float4*>(w0 + (long)j * CZ + k);
                s[j] += z4.x * w.x + z4.y * w.y + z4.z * w.z + z4.w * w.w;
            }
        }
        const float uk = p.up[kf];
        __syncthreads();
#pragma unroll
        for (int j = 0; j < 4; ++j) zbuf[r * CZ + c0 + j] += uk * tanhf(s[j]);
        __syncthreads();
    }
    // zt = z @ Wlg^T + blg -> ztlg[t]
    float s[4] = { p.blg[c0], p.blg[c0 + 1], p.blg[c0 + 2], p.blg[c0 + 3] };
    const float* w0 = p.Wlg + (long)c0 * CZ;
    for (int k = 0; k < CZ; k += 4) {
        float4 z4 = *reinterpret_cast<const float4*>(&zbuf[r * CZ + k]);
#pragma unroll
        for (int j = 0; j < 4; ++j) {
            float4 w = *reinterpret_cast<const float4*>(w0 + (long)j * CZ + k);
            s[j] += z4.x * w.x + z4.y * w.y + z4.z * w.z + z4.w * w.w;
        }
    }
    bf16* zt = p.ztlg + ((size_t)t * CB + row) * CZ + c0;
    std4(zt,     pk2(s[0], s[1]));
    std4(zt + 2, pk2(s[2], s[3]));
}

// ---------------------------------------------------------------------------
// Role loops
// ---------------------------------------------------------------------------
DEV void run_qg(const Prm& p, int s, int c, int tid, bf16* abuf)
{
    const int lane = tid & 63, wave = tid >> 6;
    const int r0 = s * 32, n0 = c * 128;
    const size_t SH = (size_t)CB * CH;
    for (int t = 0; t < CW; ++t) {
        wait8(p.qg, s * 8, t);                       // e_h[t] ready (skip t=0)
        stage32(abuf, tid, r0, p.x_b + (long)t * CIN, (long)CW * CIN,
                p.e_h + (size_t)t * SH);
        gru32(abuf, r0, n0, lane, wave, p.Wih_qb, p.Whh_qb, p.bih_q, p.bhh_q,
              p.e_f + (size_t)(t & 1) * SH,
              p.e_f + (size_t)((t + 1) & 1) * SH,
              p.e_h + (size_t)(t + 1) * SH);
        post_flag(p.qg, s * 8 + c, (u32)(t + 1));
    }
}

DEV void run_qh(const Prm& p, int h, int tid, char* smem)
{
    bf16*  abuf = (bf16*)smem;
    float* muE  = (float*)(smem + ABUF16);
    float* sigE = muE + 16 * CZ;
    float* zbuf = sigE + 16 * CZ;
    for (int i = tid; i < 16 * CZ; i += 512) zbuf[i] = 0.f;   // z(-1) = 0
    __syncthreads();
    const int lane = tid & 63, wave = tid >> 6;
    const int r0 = h * 16;
    const size_t SH = (size_t)CB * CH;
    for (int t = 0; t < CW; ++t) {
        wait8(p.qg, (h >> 1) * 8, t + 1);            // e_h[t+1]
        stage16(abuf, tid, r0, p.e_h + (size_t)(t + 1) * SH);
        ehead(abuf, lane, wave, p.Amu_q, p.Asig_q, muE, sigE);
        __syncthreads();
        zphase(p, h, t, tid, muE, sigE, zbuf);
        post_flag(p.qh, h, (u32)(t + 1));
        __syncthreads();
    }
}

DEV void run_pg(const Prm& p, int s, int c, int tid, bf16* abuf)
{
    const int lane = tid & 63, wave = tid >> 6;
    const int r0 = s * 32, n0 = c * 128;
    const size_t SH = (size_t)CB * CH, SZ = (size_t)CB * CZ;
    for (int t = 0; t < CW; ++t) {
        waitPG(p.qh, p.pg, s, t);                    // ztlg[t] + d_h[t]
        stage32(abuf, tid, r0, p.ztlg + (size_t)t * SZ, (long)CZ,
                p.d_h + (size_t)t * SH);
        gru32(abuf, r0, n0, lane, wave, p.Wih_pb, p.Whh_pb, p.bih_p, p.bhh_p,
              p.d_f + (size_t)(t & 1) * SH,
              p.d_f + (size_t)((t + 1) & 1) * SH,
              p.d_h + (size_t)(t + 1) * SH);
        post_flag(p.pg, s * 8 + c, (u32)(t + 1));
    }
}

DEV void run_ph(const Prm& p, int h, int tid, char* smem)
{
    bf16*  abuf = (bf16*)smem;
    float* muE  = (float*)(smem + ABUF16);
    float* sigE = muE + 16 * CZ;
    const int lane = tid & 63, wave = tid >> 6;
    const int r0 = h * 16;
    const size_t SH = (size_t)CB * CH;
    for (int t = 0; t < CW; ++t) {
        wait8(p.pg, (h >> 1) * 8, t + 1);            // d_h[t+1]
        stage16(abuf, tid, r0, p.d_h + (size_t)(t + 1) * SH);
        ehead(abuf, lane, wave, p.Amu_p, p.Asig_p, muE, sigE);
        __syncthreads();
        const int r = tid >> 5, c0 = (tid & 31) * 4;
        const int row = r0 + r;
#pragma unroll
        for (int j = 0; j < 4; ++j) {
            const int col = c0 + j;
            float m  = muE[r * CZ + col] + p.cmu_p[col];
            float sg = softplusf_(sigE[r * CZ + col] + p.csig_p[col]);
            float e  = p.eps_p[(size_t)row * CW * COUT + (size_t)t * COUT + col];
            p.out_o[(size_t)row * CW * COUT + (size_t)t * COUT + col] = m + sg * e;
        }
        __syncthreads();
    }
}

// ---------------------------------------------------------------------------
__launch_bounds__(512)
__global__ void mega(Prm p)
{
    extern __shared__ char smem[];
    const int wg = blockIdx.x, tid = threadIdx.x;
    if (wg < 64)       run_qg(p, wg >> 3, wg & 7, tid, (bf16*)smem);
    else if (wg < 80)  run_qh(p, wg - 64, tid, smem);
    else if (wg < 144) run_pg(p, (wg - 80) >> 3, (wg - 80) & 7, tid, (bf16*)smem);
    else               run_ph(p, wg - 144, tid, smem);
}

// ---------------------------------------------------------------------------
// Host driver
// ---------------------------------------------------------------------------
extern "C" void kernel_launch(void* const* d_in, const int* in_sizes, int n_in,
                              void* d_out, int out_size, void* d_ws, size_t ws_size,
                              hipStream_t stream)
{
    Prm p;
    const float* x      = (const float*)d_in[0];
    p.eps_q  = (const float*)d_in[1];
    p.eps_p  = (const float*)d_in[2];
    const float* Wih_q  = (const float*)d_in[3];
    const float* Whh_q  = (const float*)d_in[4];
    p.bih_q  = (const float*)d_in[5];
    p.bhh_q  = (const float*)d_in[6];
    const float* Wd_q   = (const float*)d_in[7];
    const float* bd_q   = (const float*)d_in[8];
    const float* Wmu_q  = (const float*)d_in[9];
    const float* bmu_q  = (const float*)d_in[10];
    const float* Wsig_q = (const float*)d_in[11];
    const float* bsig_q = (const float*)d_in[12];
    p.Wp     = (const float*)d_in[13];
    p.bp     = (const float*)d_in[14];
    p.up     = (const float*)d_in[15];
    p.Wlg    = (const float*)d_in[16];
    p.blg    = (const float*)d_in[17];
    const float* Wih_p  = (const float*)d_in[18];
    const float* Whh_p  = (const float*)d_in[19];
    p.bih_p  = (const float*)d_in[20];
    p.bhh_p  = (const float*)d_in[21];
    const float* Wd_p   = (const float*)d_in[22];
    const float* bd_p   = (const float*)d_in[23];
    const float* Wmu_p  = (const float*)d_in[24];
    const float* bmu_p  = (const float*)d_in[25];
    const float* Wsig_p = (const float*)d_in[26];
    const float* bsig_p = (const float*)d_in[27];

    p.out_o  = (float*)d_out;
    p.out_mu = p.out_o + (size_t)CB * CW * COUT;
    p.out_lv = p.out_mu + (size_t)CB * CW * CZ;

    char* wp_ = (char*)d_ws;
    auto carve = [&](size_t bytes) -> void* {
        void* q = (void*)wp_;
        wp_ += (bytes + 255) & ~(size_t)255;
        return q;
    };
    p.e_f  = (float*)carve((size_t)2 * CB * CH * 4);
    p.d_f  = (float*)carve((size_t)2 * CB * CH * 4);
    p.e_h  = (bf16*)carve((size_t)(CW + 1) * CB * CH * 2);
    p.d_h  = (bf16*)carve((size_t)(CW + 1) * CB * CH * 2);
    p.ztlg = (bf16*)carve((size_t)CW * CB * CZ * 2);
    p.qg   = (u32*)carve((size_t)64 * 16 * 4);
    p.qh   = (u32*)carve((size_t)16 * 16 * 4);
    p.pg   = (u32*)carve((size_t)64 * 16 * 4);
    bf16* x_b    = (bf16*)carve((size_t)CB * CW * CIN * 2);
    bf16* Wih_qb = (bf16*)carve((size_t)3 * CH * CIN * 2);
    bf16* Whh_qb = (bf16*)carve((size_t)3 * CH * CH * 2);
    bf16* Wih_pb = (bf16*)carve((size_t)3 * CH * CZ * 2);
    bf16* Whh_pb = (bf16*)carve((size_t)3 * CH * CH * 2);
    bf16* Amu_q  = (bf16*)carve((size_t)CZ * CD * 2);
    bf16* Asig_q = (bf16*)carve((size_t)CZ * CD * 2);
    bf16* Amu_p  = (bf16*)carve((size_t)COUT * CD * 2);
    bf16* Asig_p = (bf16*)carve((size_t)COUT * CD * 2);
    float* Bmu_q  = (float*)carve((size_t)CZ * CZ * 4);
    float* Bsig_q = (float*)carve((size_t)CZ * CZ * 4);
    float* cmu_q  = (float*)carve((size_t)CZ * 4);
    float* csig_q = (float*)carve((size_t)CZ * 4);
    float* cmu_p  = (float*)carve((size_t)COUT * 4);
    float* csig_p = (float*)carve((size_t)COUT * 4);
    p.x_b = x_b;       p.Wih_qb = Wih_qb; p.Whh_qb = Whh_qb;
    p.Wih_pb = Wih_pb; p.Whh_pb = Whh_pb;
    p.Amu_q = Amu_q;   p.Asig_q = Asig_q; p.Amu_p = Amu_p; p.Asig_p = Asig_p;
    p.Bmu_q = Bmu_q;   p.Bsig_q = Bsig_q;
    p.cmu_q = cmu_q;   p.csig_q = csig_q; p.cmu_p = cmu_p; p.csig_p = csig_p;

    // zero-init: states slot 0, flags
    hipMemsetAsync(p.e_f, 0, (size_t)CB * CH * 4, stream);
    hipMemsetAsync(p.d_f, 0, (size_t)CB * CH * 4, stream);
    hipMemsetAsync(p.e_h, 0, (size_t)CB * CH * 2, stream);
    hipMemsetAsync(p.d_h, 0, (size_t)CB * CH * 2, stream);
    hipMemsetAsync(p.qg, 0, (size_t)(64 + 16 + 64) * 16 * 4, stream);

    auto cvt = [&](const float* s, bf16* d, size_t n) {
        k_cvt<<<dim3((unsigned)((n / 4 + 255) / 256)), dim3(256), 0, stream>>>(s, d, (int)n);
    };
    cvt(x,      x_b,    (size_t)CB * CW * CIN);
    cvt(Wih_q,  Wih_qb, (size_t)3 * CH * CIN);
    cvt(Whh_q,  Whh_qb, (size_t)3 * CH * CH);
    cvt(Wih_p,  Wih_pb, (size_t)3 * CH * CZ);
    cvt(Whh_p,  Whh_pb, (size_t)3 * CH * CH);

    // composed heads: Q (offA=CZ in Wd_q cols; B over cols 0..CZ), P (offA=0)
    k_comp<<<dim3(128), dim3(256), 0, stream>>>(Wmu_q,  Wd_q, CZ + CH, CZ,
                                                bd_q, bmu_q,  Amu_q,  Bmu_q,  CZ, cmu_q);
    k_comp<<<dim3(128), dim3(256), 0, stream>>>(Wsig_q, Wd_q, CZ + CH, CZ,
                                                bd_q, bsig_q, Asig_q, Bsig_q, CZ, csig_q);
    k_comp<<<dim3(128), dim3(256), 0, stream>>>(Wmu_p,  Wd_p, CH, 0,
                                                bd_p, bmu_p,  Amu_p,  nullptr, 0, cmu_p);
    k_comp<<<dim3(128), dim3(256), 0, stream>>>(Wsig_p, Wd_p, CH, 0,
                                                bd_p, bsig_p, Asig_p, nullptr, 0, csig_p);

    static bool attr_set = false;
    if (!attr_set) {
        hipFuncSetAttribute((const void*)mega,
                            hipFuncAttributeMaxDynamicSharedMemorySize, SMEM_BYTES);
        attr_set = true;
    }
    mega<<<dim3(160), dim3(512), SMEM_BYTES, stream>>>(p);
}

// Round 21
// 8210.940 us; speedup vs baseline: 4.1836x; 4.1836x over previous
//
#include <hip/hip_runtime.h>

// ---------------------------------------------------------------------------
// OmniAnomaly forward, round 21: REVERT to round 18 (best proven, 7.89 ms).
// Output-column XCD ownership -> L2-resident weights (~2.5MB/XCD),
// device-scope activation writes, cached unique-address history reads.
// Q = XCDs 0-3 (cols g*256..+256 of all Q mats), P = XCDs 4-7.
// 128-WG per-side barriers. Fallback (ws<400MB): depth-2 + device-scope reads.
// B=256, W=128, IN=128, H=1024, Z=128, D=1024, OUT=128, K=3 flows
// ---------------------------------------------------------------------------

typedef __bf16 bf16;
typedef __bf16 bf16x8 __attribute__((ext_vector_type(8)));
typedef float  f32x4  __attribute__((ext_vector_type(4)));
typedef unsigned u32;

static constexpr int CB   = 256;
static constexpr int CW   = 128;
static constexpr int CIN  = 128;
static constexpr int CH   = 1024;
static constexpr int CZ   = 128;
static constexpr int CD   = 1024;
static constexpr int COUT = 128;

static constexpr int APITCH     = 1160;                      // 1152 + 8 pad
static constexpr int ABUF_BYTES = 16 * APITCH * 2;           // 37120
static constexpr int REDN       = 8 * 16 * 17;
static constexpr int RED2_BYTES = 2 * REDN * 4;              // 17408
static constexpr int FLOW_BYTES = (2 * CZ + 2 * 2 * CZ) * 4; // 3072
static constexpr int SMEM_BYTES = ABUF_BYTES + RED2_BYTES + FLOW_BYTES; // 57600

#define DEV static __device__ __forceinline__

DEV float sigmoidf_(float x) { return 1.0f / (1.0f + expf(-x)); }
DEV float softplusf_(float x) { return x > 20.0f ? x : log1pf(expf(x)); }
DEV bf16x8 ldfrag(const bf16* p) { return *reinterpret_cast<const bf16x8*>(p); }

#define MFMA(a, b, c) __builtin_amdgcn_mfma_f32_16x16x32_bf16((a), (b), (c), 0, 0, 0)

// device-coherent (sc0 sc1) accesses
DEV bf16x8 ldd16(const bf16* p) {
    bf16x8 v;
    asm volatile("global_load_dwordx4 %0, %1, off sc0 sc1\n\ts_waitcnt vmcnt(0)"
                 : "=v"(v) : "v"(p) : "memory");
    return v;
}
DEV bf16x8 ldd16_nw(const bf16* p) {
    bf16x8 v;
    asm volatile("global_load_dwordx4 %0, %1, off sc0 sc1"
                 : "=v"(v) : "v"(p) : "memory");
    return v;
}
DEV u32 ldd4(const void* p) {
    u32 v;
    asm volatile("global_load_dword %0, %1, off sc0 sc1\n\ts_waitcnt vmcnt(0)"
                 : "=v"(v) : "v"(p) : "memory");
    return v;
}
DEV void std4(void* p, u32 v) {
    asm volatile("global_store_dword %0, %1, off sc0 sc1" :: "v"(p), "v"(v) : "memory");
}
DEV void vm_wait0() {
    asm volatile("s_waitcnt vmcnt(0)" ::: "memory");
    __builtin_amdgcn_sched_barrier(0);
}
DEV u32 pk2(float a, float b) {
    union { bf16 h[2]; u32 u; } r;
    r.h[0] = (bf16)a; r.h[1] = (bf16)b;
    return r.u;
}

struct Prm {
    const float *eps_q, *eps_p;
    const float *bih_q, *bhh_q, *bd_q, *bmu_q, *bsig_q;
    const float *Wp, *bp, *up, *Wlg, *blg;
    const float *bih_p, *bhh_p, *bd_p, *bmu_p, *bsig_p;
    const bf16 *x_b, *Wih_qb, *Whh_qb, *Wd_qb, *Wmu_qb, *Wsg_qb;
    const bf16 *Wih_pb, *Whh_pb, *Wd_pb, *Wmu_pb, *Wsg_pb;
    float *e_f0, *e_f1, *d_f0, *d_f1;   // fp32 masters (WG-private patches)
    bf16 *e_h, *d_h;        // [(BIG?CW+1:2)][CB][CH]
    bf16 *dvec_h, *ddvec_h; // [(BIG?CW:1)][CB][CD]
    float *ztmp_h;          // [(BIG?CW:1)][CB][CZ]
    bf16 *zflow_h;          // [(BIG?CW+1:2)][CB][CZ]
    bf16 *ztlg_h;           // [(BIG?CW:2)][CB][CZ]
    u32 *qbar, *pbar, *zbar, *pdone;    // 128-flag arrays (16-u32 spacing)
    float *out_o, *out_mu, *out_lv;
};

// 128-WG per-side barrier (r8-proven): each of 512 threads' first 128 poll.
DEV void gbar128(u32* flg, int lwg, u32 k)
{
    asm volatile("s_waitcnt vmcnt(0)" ::: "memory");
    __syncthreads();
    if (threadIdx.x == 0)
        __hip_atomic_store(&flg[lwg * 16], k, __ATOMIC_RELAXED, __HIP_MEMORY_SCOPE_AGENT);
    if (threadIdx.x < 128) {
        while (__hip_atomic_load(&flg[threadIdx.x * 16], __ATOMIC_RELAXED,
                                 __HIP_MEMORY_SCOPE_AGENT) < k)
            __builtin_amdgcn_s_sleep(1);
    }
    __syncthreads();
}

// ---------------------------------------------------------------------------
__global__ void k_cvt(const float* __restrict__ src, bf16* __restrict__ dst, int n)
{
    int i = (blockIdx.x * blockDim.x + threadIdx.x) * 4;
    if (i < n) {
        float4 v = *reinterpret_cast<const float4*>(src + i);
        *reinterpret_cast<u32*>(dst + i)     = pk2(v.x, v.y);
        *reinterpret_cast<u32*>(dst + i + 2) = pk2(v.z, v.w);
    }
}

// ---------------------------------------------------------------------------
// Stage slab rows [r0,+16) x [head(K1) | body(1024)] into abuf.
// BIG: plain cached loads (unique addresses). FB: batched sc0sc1.
// HM: 0 = always-cached head (x_b), 1 = data head (mode-dependent).
// ---------------------------------------------------------------------------
template <bool BIG, int HM>
DEV void stage_act(bf16* abuf, int tid, int r0,
                   const bf16* head, long hs, int K1,
                   const bf16* body, long bs)
{
    if constexpr (BIG) {
        for (int j = 0; j < 4; ++j) {
            const int idx = tid + j * 512;
            const int row = idx >> 7;
            const int k = (idx & 127) * 8;
            *reinterpret_cast<bf16x8*>(abuf + (long)row * APITCH + K1 + k) =
                ldfrag(body + (long)(r0 + row) * bs + k);
        }
    } else {
        bf16x8 v[4];
        long dst[4];
#pragma unroll
        for (int j = 0; j < 4; ++j) {
            const int idx = tid + j * 512;
            const int row = idx >> 7;
            const int k = (idx & 127) * 8;
            v[j] = ldd16_nw(body + (long)(r0 + row) * bs + k);
            dst[j] = (long)row * APITCH + K1 + k;
        }
        vm_wait0();
#pragma unroll
        for (int j = 0; j < 4; ++j)
            *reinterpret_cast<bf16x8*>(abuf + dst[j]) = v[j];
    }
    if (K1 > 0) {
        const int HC = K1 >> 3;
        for (int idx = tid; idx < 16 * HC; idx += 512) {
            const int row = idx / HC;
            const int k = (idx - row * HC) * 8;
            const bf16* s = head + (long)(r0 + row) * hs + k;
            bf16x8 hv;
            if constexpr (HM == 0) hv = ldfrag(s);
            else                   hv = BIG ? ldfrag(s) : ldd16(s);
            *reinterpret_cast<bf16x8*>(abuf + (long)row * APITCH + k) = hv;
        }
    }
    __syncthreads();
}

// ---------------------------------------------------------------------------
// GRU compute (r17 prefetch version; weights plain cached -> L2-resident).
// ---------------------------------------------------------------------------
DEV void gru_compute(const bf16* abuf, int r0, int n0, int lane, int wave,
                     const bf16* __restrict__ Wih, const bf16* __restrict__ Whh,
                     const float* __restrict__ bih, const float* __restrict__ bhh,
                     const float* __restrict__ Efin,
                     float* __restrict__ Efo, bf16* __restrict__ Ebo)
{
    const int lr = lane & 15, lkE = (lane >> 4) * 8;
    const int c = n0 + wave * 16 + lr;
    const bf16* arow = abuf + (long)lr * APITCH;

    f32x4 acc[4] = {};
    {
        bf16x8 wv[4][3];
#pragma unroll
        for (int j = 0; j < 4; ++j)
#pragma unroll
            for (int g = 0; g < 3; ++g)
                wv[j][g] = ldfrag(Wih + ((long)g * CH + c) * CIN + j * 32 + lkE);
#pragma unroll
        for (int j = 0; j < 4; ++j) {
            bf16x8 a = *reinterpret_cast<const bf16x8*>(arow + j * 32 + lkE);
            acc[0] = MFMA(a, wv[j][0], acc[0]);
            acc[1] = MFMA(a, wv[j][1], acc[1]);
            acc[2] = MFMA(a, wv[j][2], acc[2]);
        }
    }
    {
        const bf16* wp0 = Whh + ((long)0 * CH + c) * CH + lkE;
        const bf16* wp1 = Whh + ((long)1 * CH + c) * CH + lkE;
        const bf16* wp2 = Whh + ((long)2 * CH + c) * CH + lkE;
        bf16x8 wv[4][3];
#pragma unroll
        for (int j = 0; j < 4; ++j) {
            wv[j][0] = ldfrag(wp0 + j * 32);
            wv[j][1] = ldfrag(wp1 + j * 32);
            wv[j][2] = ldfrag(wp2 + j * 32);
        }
#pragma unroll
        for (int kb = 0; kb < 32; ++kb) {
            const int sl = kb & 3;
            bf16x8 a = *reinterpret_cast<const bf16x8*>(arow + CIN + kb * 32 + lkE);
            acc[0] = MFMA(a, wv[sl][0], acc[0]);
            acc[1] = MFMA(a, wv[sl][1], acc[1]);
            acc[3] = MFMA(a, wv[sl][2], acc[3]);
            if (kb < 28) {
                wv[sl][0] = ldfrag(wp0 + (kb + 4) * 32);
                wv[sl][1] = ldfrag(wp1 + (kb + 4) * 32);
                wv[sl][2] = ldfrag(wp2 + (kb + 4) * 32);
            }
        }
    }

    const float b0r = bih[c] + bhh[c];
    const float b0z = bih[CH + c] + bhh[CH + c];
    const float bin = bih[2 * CH + c];
    const float bhn = bhh[2 * CH + c];
    const int rbase = r0 + (lane >> 4) * 4;
#pragma unroll
    for (int i = 0; i < 4; ++i) {
        const int row = rbase + i;
        float r = sigmoidf_(acc[0][i] + b0r);
        float u = sigmoidf_(acc[1][i] + b0z);
        float n = tanhf(acc[2][i] + bin + r * (acc[3][i] + bhn));
        float en = (1.0f - u) * n + u * Efin[(long)row * CH + c];
        Efo[(long)row * CH + c] = en;
        float vB = __shfl_xor(en, 1);
        if (!(lane & 1))
            std4(Ebo + (long)row * CH + c, pk2(en, vB));
    }
}

// ---------------------------------------------------------------------------
DEV void lin_compute(const bf16* abuf, int r0, int n0, int lane, int wave, int Ktot,
                     const bf16* __restrict__ W,
                     const float* __restrict__ bias, bf16* __restrict__ Out)
{
    const int lr = lane & 15, lkE = (lane >> 4) * 8;
    const int c = n0 + wave * 16 + lr;
    const bf16* arow = abuf + (long)lr * APITCH;
    const bf16* wrow = W + (long)c * Ktot;
    const int kofs = Ktot - CH;

    f32x4 acc = {};
    {
        const bf16* wp = wrow + kofs + lkE;
        bf16x8 wv[8];
#pragma unroll
        for (int j = 0; j < 8; ++j) wv[j] = ldfrag(wp + j * 32);
#pragma unroll
        for (int kb = 0; kb < 32; ++kb) {
            const int sl = kb & 7;
            bf16x8 a = *reinterpret_cast<const bf16x8*>(arow + kofs + kb * 32 + lkE);
            acc = MFMA(a, wv[sl], acc);
            if (kb < 24) wv[sl] = ldfrag(wp + (kb + 8) * 32);
        }
    }
    if (Ktot > CH) {
        bf16x8 wv[4];
#pragma unroll
        for (int j = 0; j < 4; ++j) wv[j] = ldfrag(wrow + j * 32 + lkE);
#pragma unroll
        for (int j = 0; j < 4; ++j) {
            bf16x8 a = *reinterpret_cast<const bf16x8*>(arow + j * 32 + lkE);
            acc = MFMA(a, wv[j], acc);
        }
    }

    const float bb = bias[c];
    const int rbase = r0 + (lane >> 4) * 4;
#pragma unroll
    for (int i = 0; i < 4; ++i) {
        float v = acc[i] + bb;
        float vB = __shfl_xor(v, 1);
        if (!(lane & 1))
            std4(Out + (long)(rbase + i) * CD + c, pk2(v, vB));
    }
}

// ---------------------------------------------------------------------------
// Two-head tail: rows [mb,+16) x cols [nb,+16), 8-wave K-split, LDS reduce.
// ---------------------------------------------------------------------------
template <bool BIG, int MODE>
DEV void phase_tail2(const Prm& p, int t, int mb, int nb, int tid,
                     int lane, int wave, float* Ra, float* Rs,
                     const bf16* __restrict__ A, float* __restrict__ ztmp,
                     const bf16* __restrict__ Wa, const bf16* __restrict__ Wb,
                     const float* __restrict__ ba, const float* __restrict__ bb)
{
    const int lr = lane & 15, lkE = (lane >> 4) * 8;
    f32x4 am = {}, as = {};
    const int k0 = wave * 128;
    bf16x8 av[4], bmv[4], bsv[4];
#pragma unroll
    for (int j = 0; j < 4; ++j) {
        const int k = k0 + j * 32;
        const bf16* ap = A + (long)(mb + lr) * CD + k + lkE;
        av[j]  = BIG ? ldfrag(ap) : ldd16_nw(ap);
        bmv[j] = ldfrag(Wa + (long)(nb + lr) * CD + k + lkE);
        bsv[j] = ldfrag(Wb + (long)(nb + lr) * CD + k + lkE);
    }
    if constexpr (!BIG) vm_wait0();
#pragma unroll
    for (int j = 0; j < 4; ++j) {
        am = MFMA(av[j], bmv[j], am);
        as = MFMA(av[j], bsv[j], as);
    }
    __syncthreads();
#pragma unroll
    for (int i = 0; i < 4; ++i) {
        Ra[(wave * 16 + (lane >> 4) * 4 + i) * 17 + lr] = am[i];
        Rs[(wave * 16 + (lane >> 4) * 4 + i) * 17 + lr] = as[i];
    }
    __syncthreads();
    if (tid < 256) {
        const int trow = tid >> 4, tcol = tid & 15;
        float vm = 0.f, vs = 0.f;
#pragma unroll
        for (int w = 0; w < 8; ++w) {
            vm += Ra[(w * 16 + trow) * 17 + tcol];
            vs += Rs[(w * 16 + trow) * 17 + tcol];
        }
        const int row = mb + trow, col = nb + tcol;
        if constexpr (MODE == 0) {
            float mu = vm + ba[col];
            float lv = softplusf_(vs + bb[col]);
            float e  = p.eps_q[(long)row * CW * CZ + (long)t * CZ + col];
            float z  = mu + expf(0.5f * lv) * e;
            p.out_mu[(long)row * CW * CZ + (long)t * CZ + col] = mu;
            p.out_lv[(long)row * CW * CZ + (long)t * CZ + col] = lv;
            std4(ztmp + (long)row * CZ + col, __float_as_uint(z));
        } else {
            float m  = vm + ba[col];
            float sg = softplusf_(vs + bb[col]);
            float e  = p.eps_p[(long)row * CW * COUT + (long)t * COUT + col];
            p.out_o[(long)row * CW * COUT + (long)t * COUT + col] = m + sg * e;
        }
    }
}

// ---------------------------------------------------------------------------
// Planar flows + LGSSM: 2 rows/WG.
// ---------------------------------------------------------------------------
template <bool BIG>
DEV void phase_flows2(const Prm& p, int rowbase, int tid, int t, float* zl, float* ps,
                      const float* __restrict__ ztmp,
                      bf16* __restrict__ ztlg, bf16* __restrict__ zflow_next)
{
    const int rg = tid >> 8;
    const int sub = tid & 255;
    const int c = sub & 127, half = sub >> 7;
    const int row = rowbase + rg;
    float* zrow = zl + rg * CZ;
    float* pall = ps + rg * 2 * CZ;

    if (half == 0)
        zrow[c] = BIG ? ztmp[(long)row * CZ + c]
                      : __uint_as_float(ldd4(ztmp + (long)row * CZ + c));
    __syncthreads();

#pragma unroll 1
    for (int kf = 0; kf < 3; ++kf) {
        const float* wr = p.Wp + ((long)kf * CZ + c) * CZ + half * 64;
        const float* zh = zrow + half * 64;
        float s = 0.f;
#pragma unroll
        for (int j = 0; j < 64; j += 4) {
            float4 w = *reinterpret_cast<const float4*>(wr + j);
            s += zh[j] * w.x + zh[j + 1] * w.y + zh[j + 2] * w.z + zh[j + 3] * w.w;
        }
        pall[half * CZ + c] = s;
        __syncthreads();
        if (half == 0) {
            float sf = pall[c] + pall[CZ + c] + p.bp[kf * CZ + c];
            zrow[c] += p.up[kf] * tanhf(sf);
        }
        __syncthreads();
    }
    {
        const float* wr = p.Wlg + (long)c * CZ + half * 64;
        const float* zh = zrow + half * 64;
        float s = 0.f;
#pragma unroll
        for (int j = 0; j < 64; j += 4) {
            float4 w = *reinterpret_cast<const float4*>(wr + j);
            s += zh[j] * w.x + zh[j + 1] * w.y + zh[j + 2] * w.z + zh[j + 3] * w.w;
        }
        pall[half * CZ + c] = s;
        __syncthreads();
        if (half == 0) {
            float zt = pall[c] + pall[CZ + c] + p.blg[c];
            float ztB = __shfl_xor(zt, 1);
            if (!(c & 1)) {
                std4(ztlg + (long)row * CZ + c, pk2(zt, ztB));
                std4(zflow_next + (long)row * CZ + c, pk2(zrow[c], zrow[c + 1]));
            }
        }
    }
}

// ---------------------------------------------------------------------------
template <bool BIG>
DEV void run_q(const Prm& p, int lwg, int tid,
               bf16* abuf, float* Ra, float* Rs, float* ZLp, float* PSp)
{
    const int lane = tid & 63, wave = tid >> 6;
    const int g = lwg >> 5, m = lwg & 31;
    const int r0 = (m >> 1) * 16;
    const int n0 = g * 256 + (m & 1) * 128;
    const int nt = g * 32 + (m & 1) * 16;
    const size_t SH = (size_t)CB * CH, SD = (size_t)CB * CD, SZ = (size_t)CB * CZ;
    u32 bk = 0;
#pragma unroll 1
    for (int t = 0; t < CW; ++t) {
        const int eIn  = BIG ? t : (t & 1);
        const int eOut = BIG ? (t + 1) : ((t + 1) & 1);
        const int dT   = BIG ? t : 0;
        const int zT   = BIG ? t : (t & 1);
        const float* ef_i = (t & 1) ? p.e_f1 : p.e_f0;
        float*       ef_o = (t & 1) ? p.e_f0 : p.e_f1;

        stage_act<BIG, 0>(abuf, tid, r0, p.x_b + (long)t * CIN, (long)CW * CIN,
                          CIN, p.e_h + (size_t)eIn * SH, CH);
        gru_compute(abuf, r0, n0, lane, wave, p.Wih_qb, p.Whh_qb,
                    p.bih_q, p.bhh_q, ef_i, ef_o, p.e_h + (size_t)eOut * SH);
        gbar128(p.qbar, lwg, ++bk);

        stage_act<BIG, 1>(abuf, tid, r0, p.zflow_h + (size_t)eIn * SZ, CZ, CZ,
                          p.e_h + (size_t)eOut * SH, CH);
        lin_compute(abuf, r0, n0, lane, wave, CZ + CH, p.Wd_qb, p.bd_q,
                    p.dvec_h + (size_t)dT * SD);
        gbar128(p.qbar, lwg, ++bk);

        phase_tail2<BIG, 0>(p, t, r0, nt, tid, lane, wave, Ra, Rs,
                            p.dvec_h + (size_t)dT * SD, p.ztmp_h + (size_t)dT * SZ,
                            p.Wmu_qb, p.Wsg_qb, p.bmu_q, p.bsig_q);
        gbar128(p.qbar, lwg, ++bk);

        if constexpr (!BIG) {
            if (t >= 2) {
                if (tid < 128) {
                    while ((int)__hip_atomic_load(&p.pdone[tid * 16], __ATOMIC_RELAXED,
                                                  __HIP_MEMORY_SCOPE_AGENT) < t - 1)
                        __builtin_amdgcn_s_sleep(2);
                }
                __syncthreads();
            }
        }
        phase_flows2<BIG>(p, lwg * 2, tid, t, ZLp, PSp,
                          p.ztmp_h + (size_t)dT * SZ,
                          p.ztlg_h + (size_t)zT * SZ,
                          p.zflow_h + (size_t)eOut * SZ);
        asm volatile("s_waitcnt vmcnt(0)" ::: "memory");
        __syncthreads();
        if (tid == 0)
            __hip_atomic_store(&p.zbar[lwg * 16], (u32)(t + 1),
                               __ATOMIC_RELAXED, __HIP_MEMORY_SCOPE_AGENT);
        __syncthreads();
    }
}

template <bool BIG>
DEV void run_p(const Prm& p, int lwg, int tid,
               bf16* abuf, float* Ra, float* Rs)
{
    const int lane = tid & 63, wave = tid >> 6;
    const int g = lwg >> 5, m = lwg & 31;
    const int r0 = (m >> 1) * 16;
    const int n0 = g * 256 + (m & 1) * 128;
    const int nt = g * 32 + (m & 1) * 16;
    const size_t SH = (size_t)CB * CH, SD = (size_t)CB * CD, SZ = (size_t)CB * CZ;
    u32 bk = 0;
#pragma unroll 1
    for (int t = 0; t < CW; ++t) {
        if (tid < 128) {
            while (__hip_atomic_load(&p.zbar[tid * 16], __ATOMIC_RELAXED,
                                     __HIP_MEMORY_SCOPE_AGENT) < (u32)(t + 1))
                __builtin_amdgcn_s_sleep(2);
        }
        __syncthreads();

        const int sIn  = BIG ? t : (t & 1);
        const int sOut = BIG ? (t + 1) : ((t + 1) & 1);
        const int dT   = BIG ? t : 0;
        const int zT   = BIG ? t : (t & 1);
        const float* df_i = (t & 1) ? p.d_f1 : p.d_f0;
        float*       df_o = (t & 1) ? p.d_f0 : p.d_f1;

        stage_act<BIG, 1>(abuf, tid, r0, p.ztlg_h + (size_t)zT * SZ, CZ, CZ,
                          p.d_h + (size_t)sIn * SH, CH);
        gru_compute(abuf, r0, n0, lane, wave, p.Wih_pb, p.Whh_pb,
                    p.bih_p, p.bhh_p, df_i, df_o, p.d_h + (size_t)sOut * SH);
        gbar128(p.pbar, lwg, ++bk);
        if constexpr (!BIG) {
            if (tid == 0)
                __hip_atomic_store(&p.pdone[lwg * 16], (u32)(t + 1),
                                   __ATOMIC_RELAXED, __HIP_MEMORY_SCOPE_AGENT);
        }

        stage_act<BIG, 0>(abuf, tid, r0, nullptr, 0, 0,
                          p.d_h + (size_t)sOut * SH, CH);
        lin_compute(abuf, r0, n0, lane, wave, CH, p.Wd_pb, p.bd_p,
                    p.ddvec_h + (size_t)dT * SD);
        gbar128(p.pbar, lwg, ++bk);

        phase_tail2<BIG, 1>(p, t, r0, nt, tid, lane, wave, Ra, Rs,
                            p.ddvec_h + (size_t)dT * SD, nullptr,
                            p.Wmu_pb, p.Wsg_pb, p.bmu_p, p.bsig_p);
        // ddvec reuse (FB) protected by next barP after GRU(t+1)
    }
}

// ---------------------------------------------------------------------------
template <bool BIG>
__launch_bounds__(512)
__global__ void mega(Prm p)
{
    extern __shared__ char smem[];
    bf16*  abuf = (bf16*)smem;
    float* Ra   = (float*)(smem + ABUF_BYTES);
    float* Rs   = Ra + REDN;
    float* ZLp  = (float*)(smem + ABUF_BYTES + RED2_BYTES);
    float* PSp  = ZLp + 2 * CZ;

    const int wg = blockIdx.x, tid = threadIdx.x;
    const int gid = wg & 7, m = wg >> 3;          // m 0..31
    const bool isQ = gid < 4;
    const int lwg = (isQ ? gid : gid - 4) * 32 + m;   // 0..127 per side

    if (isQ) run_q<BIG>(p, lwg, tid, abuf, Ra, Rs, ZLp, PSp);
    else     run_p<BIG>(p, lwg, tid, abuf, Ra, Rs);
}

// ---------------------------------------------------------------------------
// Host driver
// ---------------------------------------------------------------------------
extern "C" void kernel_launch(void* const* d_in, const int* in_sizes, int n_in,
                              void* d_out, int out_size, void* d_ws, size_t ws_size,
                              hipStream_t stream)
{
    Prm p;
    const float* x      = (const float*)d_in[0];
    p.eps_q  = (const float*)d_in[1];
    p.eps_p  = (const float*)d_in[2];
    const float* Wih_q  = (const float*)d_in[3];
    const float* Whh_q  = (const float*)d_in[4];
    p.bih_q  = (const float*)d_in[5];
    p.bhh_q  = (const float*)d_in[6];
    const float* Wd_q   = (const float*)d_in[7];
    p.bd_q   = (const float*)d_in[8];
    const float* Wmu_q  = (const float*)d_in[9];
    p.bmu_q  = (const float*)d_in[10];
    const float* Wsig_q = (const float*)d_in[11];
    p.bsig_q = (const float*)d_in[12];
    p.Wp     = (const float*)d_in[13];
    p.bp     = (const float*)d_in[14];
    p.up     = (const float*)d_in[15];
    p.Wlg    = (const float*)d_in[16];
    p.blg    = (const float*)d_in[17];
    const float* Wih_p  = (const float*)d_in[18];
    const float* Whh_p  = (const float*)d_in[19];
    p.bih_p  = (const float*)d_in[20];
    p.bhh_p  = (const float*)d_in[21];
    const float* Wd_p   = (const float*)d_in[22];
    p.bd_p   = (const float*)d_in[23];
    const float* Wmu_p  = (const float*)d_in[24];
    p.bmu_p  = (const float*)d_in[25];
    const float* Wsig_p = (const float*)d_in[26];
    p.bsig_p = (const float*)d_in[27];

    p.out_o  = (float*)d_out;
    p.out_mu = p.out_o + (size_t)CB * CW * COUT;
    p.out_lv = p.out_mu + (size_t)CB * CW * CZ;

    const bool BIGM = ws_size >= (size_t)400 * 1024 * 1024;
    const int NS = BIGM ? (CW + 1) : 2;
    const int NT = BIGM ? CW : 1;
    const int NZ = BIGM ? CW : 2;

    char* wp_ = (char*)d_ws;
    auto carve = [&](size_t bytes) -> void* {
        void* q = (void*)wp_;
        wp_ += (bytes + 255) & ~(size_t)255;
        return q;
    };
    p.e_f0 = (float*)carve((size_t)CB * CH * 4);
    p.e_f1 = (float*)carve((size_t)CB * CH * 4);
    p.d_f0 = (float*)carve((size_t)CB * CH * 4);
    p.d_f1 = (float*)carve((size_t)CB * CH * 4);
    p.e_h     = (bf16*)carve((size_t)NS * CB * CH * 2);
    p.d_h     = (bf16*)carve((size_t)NS * CB * CH * 2);
    p.dvec_h  = (bf16*)carve((size_t)NT * CB * CD * 2);
    p.ddvec_h = (bf16*)carve((size_t)NT * CB * CD * 2);
    p.ztmp_h  = (float*)carve((size_t)NT * CB * CZ * 4);
    p.zflow_h = (bf16*)carve((size_t)NS * CB * CZ * 2);
    p.ztlg_h  = (bf16*)carve((size_t)NZ * CB * CZ * 2);
    p.qbar    = (u32*)carve((size_t)128 * 16 * 4);
    p.pbar    = (u32*)carve((size_t)128 * 16 * 4);
    p.zbar    = (u32*)carve((size_t)128 * 16 * 4);
    p.pdone   = (u32*)carve((size_t)128 * 16 * 4);
    bf16* x_b    = (bf16*)carve((size_t)CB * CW * CIN * 2);
    bf16* Wih_qb = (bf16*)carve((size_t)3 * CH * CIN * 2);
    bf16* Whh_qb = (bf16*)carve((size_t)3 * CH * CH * 2);
    bf16* Wd_qb  = (bf16*)carve((size_t)CD * (CZ + CH) * 2);
    bf16* Wmu_qb = (bf16*)carve((size_t)CZ * CD * 2);
    bf16* Wsg_qb = (bf16*)carve((size_t)CZ * CD * 2);
    bf16* Wih_pb = (bf16*)carve((size_t)3 * CH * CZ * 2);
    bf16* Whh_pb = (bf16*)carve((size_t)3 * CH * CH * 2);
    bf16* Wd_pb  = (bf16*)carve((size_t)CD * CH * 2);
    bf16* Wmu_pb = (bf16*)carve((size_t)COUT * CD * 2);
    bf16* Wsg_pb = (bf16*)carve((size_t)COUT * CD * 2);
    p.x_b = x_b;       p.Wih_qb = Wih_qb; p.Whh_qb = Whh_qb;
    p.Wd_qb = Wd_qb;   p.Wmu_qb = Wmu_qb; p.Wsg_qb = Wsg_qb;
    p.Wih_pb = Wih_pb; p.Whh_pb = Whh_pb; p.Wd_pb = Wd_pb;
    p.Wmu_pb = Wmu_pb; p.Wsg_pb = Wsg_pb;

    hipMemsetAsync(p.e_f0, 0, (size_t)CB * CH * 4, stream);
    hipMemsetAsync(p.d_f0, 0, (size_t)CB * CH * 4, stream);
    hipMemsetAsync(p.e_h, 0, (size_t)CB * CH * 2, stream);      // slot 0
    hipMemsetAsync(p.d_h, 0, (size_t)CB * CH * 2, stream);
    hipMemsetAsync(p.zflow_h, 0, (size_t)CB * CZ * 2, stream);  // slot 0
    hipMemsetAsync(p.qbar, 0, (size_t)128 * 16 * 4, stream);
    hipMemsetAsync(p.pbar, 0, (size_t)128 * 16 * 4, stream);
    hipMemsetAsync(p.zbar, 0, (size_t)128 * 16 * 4, stream);
    hipMemsetAsync(p.pdone, 0, (size_t)128 * 16 * 4, stream);

    auto cvt = [&](const float* s, bf16* d, size_t n) {
        k_cvt<<<dim3((unsigned)((n / 4 + 255) / 256)), dim3(256), 0, stream>>>(s, d, (int)n);
    };
    cvt(x,      x_b,    (size_t)CB * CW * CIN);
    cvt(Wih_q,  Wih_qb, (size_t)3 * CH * CIN);
    cvt(Whh_q,  Whh_qb, (size_t)3 * CH * CH);
    cvt(Wd_q,   Wd_qb,  (size_t)CD * (CZ + CH));
    cvt(Wmu_q,  Wmu_qb, (size_t)CZ * CD);
    cvt(Wsig_q, Wsg_qb, (size_t)CZ * CD);
    cvt(Wih_p,  Wih_pb, (size_t)3 * CH * CZ);
    cvt(Whh_p,  Whh_pb, (size_t)3 * CH * CH);
    cvt(Wd_p,   Wd_pb,  (size_t)CD * CH);
    cvt(Wmu_p,  Wmu_pb, (size_t)COUT * CD);
    cvt(Wsig_p, Wsg_pb, (size_t)COUT * CD);

    if (BIGM)
        mega<true><<<dim3(256), dim3(512), SMEM_BYTES, stream>>>(p);
    else
        mega<false><<<dim3(256), dim3(512), SMEM_BYTES, stream>>>(p);
}

// Round 23
// 8190.605 us; speedup vs baseline: 4.1939x; 1.0025x over previous
//
#include <hip/hip_runtime.h>

// ---------------------------------------------------------------------------
// OmniAnomaly forward, round 23: r22 fix (compile error — overload visibility).
// r18/r21 structure with Q3+Q4 fused in BIG mode: each Q-WG computes both
// heads for its own 2 flow-rows (redundant per-row compute, weights
// L2-resident) -> removes one 128-WG barrier and the ztmp round-trip/step.
// P-side and FB path identical to r18.
// B=256, W=128, IN=128, H=1024, Z=128, D=1024, OUT=128, K=3 flows
// ---------------------------------------------------------------------------

typedef __bf16 bf16;
typedef __bf16 bf16x8 __attribute__((ext_vector_type(8)));
typedef float  f32x4  __attribute__((ext_vector_type(4)));
typedef unsigned u32;

static constexpr int CB   = 256;
static constexpr int CW   = 128;
static constexpr int CIN  = 128;
static constexpr int CH   = 1024;
static constexpr int CZ   = 128;
static constexpr int CD   = 1024;
static constexpr int COUT = 128;

static constexpr int APITCH     = 1160;                      // 1152 + 8 pad
static constexpr int ABUF_BYTES = 16 * APITCH * 2;           // 37120
static constexpr int REDN       = 8 * 16 * 17;
static constexpr int RED2_BYTES = 2 * REDN * 4;              // 17408
static constexpr int FLOW_BYTES = (2 * CZ + 2 * 2 * CZ) * 4; // 3072
static constexpr int SMEM_BYTES = ABUF_BYTES + RED2_BYTES + FLOW_BYTES; // 57600

#define DEV static __device__ __forceinline__

DEV float sigmoidf_(float x) { return 1.0f / (1.0f + expf(-x)); }
DEV float softplusf_(float x) { return x > 20.0f ? x : log1pf(expf(x)); }
DEV bf16x8 ldfrag(const bf16* p) { return *reinterpret_cast<const bf16x8*>(p); }

#define MFMA(a, b, c) __builtin_amdgcn_mfma_f32_16x16x32_bf16((a), (b), (c), 0, 0, 0)

// device-coherent (sc0 sc1) accesses
DEV bf16x8 ldd16(const bf16* p) {
    bf16x8 v;
    asm volatile("global_load_dwordx4 %0, %1, off sc0 sc1\n\ts_waitcnt vmcnt(0)"
                 : "=v"(v) : "v"(p) : "memory");
    return v;
}
DEV bf16x8 ldd16_nw(const bf16* p) {
    bf16x8 v;
    asm volatile("global_load_dwordx4 %0, %1, off sc0 sc1"
                 : "=v"(v) : "v"(p) : "memory");
    return v;
}
DEV u32 ldd4(const void* p) {
    u32 v;
    asm volatile("global_load_dword %0, %1, off sc0 sc1\n\ts_waitcnt vmcnt(0)"
                 : "=v"(v) : "v"(p) : "memory");
    return v;
}
DEV void std4(void* p, u32 v) {
    asm volatile("global_store_dword %0, %1, off sc0 sc1" :: "v"(p), "v"(v) : "memory");
}
DEV void vm_wait0() {
    asm volatile("s_waitcnt vmcnt(0)" ::: "memory");
    __builtin_amdgcn_sched_barrier(0);
}
DEV u32 pk2(float a, float b) {
    union { bf16 h[2]; u32 u; } r;
    r.h[0] = (bf16)a; r.h[1] = (bf16)b;
    return r.u;
}

struct Prm {
    const float *eps_q, *eps_p;
    const float *bih_q, *bhh_q, *bd_q, *bmu_q, *bsig_q;
    const float *Wp, *bp, *up, *Wlg, *blg;
    const float *bih_p, *bhh_p, *bd_p, *bmu_p, *bsig_p;
    const bf16 *x_b, *Wih_qb, *Whh_qb, *Wd_qb, *Wmu_qb, *Wsg_qb;
    const bf16 *Wih_pb, *Whh_pb, *Wd_pb, *Wmu_pb, *Wsg_pb;
    float *e_f0, *e_f1, *d_f0, *d_f1;
    bf16 *e_h, *d_h;        // [(BIG?CW+1:2)][CB][CH]
    bf16 *dvec_h, *ddvec_h; // [(BIG?CW:1)][CB][CD]
    float *ztmp_h;          // [(BIG?CW:1)][CB][CZ] (FB only)
    bf16 *zflow_h;          // [(BIG?CW+1:2)][CB][CZ]
    bf16 *ztlg_h;           // [(BIG?CW:2)][CB][CZ]
    u32 *qbar, *pbar, *zbar, *pdone;
    float *out_o, *out_mu, *out_lv;
};

// 128-WG per-side barrier (r8-proven).
DEV void gbar128(u32* flg, int lwg, u32 k)
{
    asm volatile("s_waitcnt vmcnt(0)" ::: "memory");
    __syncthreads();
    if (threadIdx.x == 0)
        __hip_atomic_store(&flg[lwg * 16], k, __ATOMIC_RELAXED, __HIP_MEMORY_SCOPE_AGENT);
    if (threadIdx.x < 128) {
        while (__hip_atomic_load(&flg[threadIdx.x * 16], __ATOMIC_RELAXED,
                                 __HIP_MEMORY_SCOPE_AGENT) < k)
            __builtin_amdgcn_s_sleep(1);
    }
    __syncthreads();
}

// ---------------------------------------------------------------------------
__global__ void k_cvt(const float* __restrict__ src, bf16* __restrict__ dst, int n)
{
    int i = (blockIdx.x * blockDim.x + threadIdx.x) * 4;
    if (i < n) {
        float4 v = *reinterpret_cast<const float4*>(src + i);
        *reinterpret_cast<u32*>(dst + i)     = pk2(v.x, v.y);
        *reinterpret_cast<u32*>(dst + i + 2) = pk2(v.z, v.w);
    }
}

// ---------------------------------------------------------------------------
// Stage slab rows [r0,+16) x [head(K1) | body(1024)] into abuf.
// BIG: plain cached loads (unique addresses). FB: batched sc0sc1.
// HM: 0 = always-cached head (x_b), 1 = data head (mode-dependent).
// ---------------------------------------------------------------------------
template <bool BIG, int HM>
DEV void stage_act(bf16* abuf, int tid, int r0,
                   const bf16* head, long hs, int K1,
                   const bf16* body, long bs)
{
    if constexpr (BIG) {
        for (int j = 0; j < 4; ++j) {
            const int idx = tid + j * 512;
            const int row = idx >> 7;
            const int k = (idx & 127) * 8;
            *reinterpret_cast<bf16x8*>(abuf + (long)row * APITCH + K1 + k) =
                ldfrag(body + (long)(r0 + row) * bs + k);
        }
    } else {
        bf16x8 v[4];
        long dst[4];
#pragma unroll
        for (int j = 0; j < 4; ++j) {
            const int idx = tid + j * 512;
            const int row = idx >> 7;
            const int k = (idx & 127) * 8;
            v[j] = ldd16_nw(body + (long)(r0 + row) * bs + k);
            dst[j] = (long)row * APITCH + K1 + k;
        }
        vm_wait0();
#pragma unroll
        for (int j = 0; j < 4; ++j)
            *reinterpret_cast<bf16x8*>(abuf + dst[j]) = v[j];
    }
    if (K1 > 0) {
        const int HC = K1 >> 3;
        for (int idx = tid; idx < 16 * HC; idx += 512) {
            const int row = idx / HC;
            const int k = (idx - row * HC) * 8;
            const bf16* s = head + (long)(r0 + row) * hs + k;
            bf16x8 hv;
            if constexpr (HM == 0) hv = ldfrag(s);
            else                   hv = BIG ? ldfrag(s) : ldd16(s);
            *reinterpret_cast<bf16x8*>(abuf + (long)row * APITCH + k) = hv;
        }
    }
    __syncthreads();
}

// ---------------------------------------------------------------------------
DEV void gru_compute(const bf16* abuf, int r0, int n0, int lane, int wave,
                     const bf16* __restrict__ Wih, const bf16* __restrict__ Whh,
                     const float* __restrict__ bih, const float* __restrict__ bhh,
                     const float* __restrict__ Efin,
                     float* __restrict__ Efo, bf16* __restrict__ Ebo)
{
    const int lr = lane & 15, lkE = (lane >> 4) * 8;
    const int c = n0 + wave * 16 + lr;
    const bf16* arow = abuf + (long)lr * APITCH;

    f32x4 acc[4] = {};
    {
        bf16x8 wv[4][3];
#pragma unroll
        for (int j = 0; j < 4; ++j)
#pragma unroll
            for (int g = 0; g < 3; ++g)
                wv[j][g] = ldfrag(Wih + ((long)g * CH + c) * CIN + j * 32 + lkE);
#pragma unroll
        for (int j = 0; j < 4; ++j) {
            bf16x8 a = *reinterpret_cast<const bf16x8*>(arow + j * 32 + lkE);
            acc[0] = MFMA(a, wv[j][0], acc[0]);
            acc[1] = MFMA(a, wv[j][1], acc[1]);
            acc[2] = MFMA(a, wv[j][2], acc[2]);
        }
    }
    {
        const bf16* wp0 = Whh + ((long)0 * CH + c) * CH + lkE;
        const bf16* wp1 = Whh + ((long)1 * CH + c) * CH + lkE;
        const bf16* wp2 = Whh + ((long)2 * CH + c) * CH + lkE;
        bf16x8 wv[4][3];
#pragma unroll
        for (int j = 0; j < 4; ++j) {
            wv[j][0] = ldfrag(wp0 + j * 32);
            wv[j][1] = ldfrag(wp1 + j * 32);
            wv[j][2] = ldfrag(wp2 + j * 32);
        }
#pragma unroll
        for (int kb = 0; kb < 32; ++kb) {
            const int sl = kb & 3;
            bf16x8 a = *reinterpret_cast<const bf16x8*>(arow + CIN + kb * 32 + lkE);
            acc[0] = MFMA(a, wv[sl][0], acc[0]);
            acc[1] = MFMA(a, wv[sl][1], acc[1]);
            acc[3] = MFMA(a, wv[sl][2], acc[3]);
            if (kb < 28) {
                wv[sl][0] = ldfrag(wp0 + (kb + 4) * 32);
                wv[sl][1] = ldfrag(wp1 + (kb + 4) * 32);
                wv[sl][2] = ldfrag(wp2 + (kb + 4) * 32);
            }
        }
    }

    const float b0r = bih[c] + bhh[c];
    const float b0z = bih[CH + c] + bhh[CH + c];
    const float bin = bih[2 * CH + c];
    const float bhn = bhh[2 * CH + c];
    const int rbase = r0 + (lane >> 4) * 4;
#pragma unroll
    for (int i = 0; i < 4; ++i) {
        const int row = rbase + i;
        float r = sigmoidf_(acc[0][i] + b0r);
        float u = sigmoidf_(acc[1][i] + b0z);
        float n = tanhf(acc[2][i] + bin + r * (acc[3][i] + bhn));
        float en = (1.0f - u) * n + u * Efin[(long)row * CH + c];
        Efo[(long)row * CH + c] = en;
        float vB = __shfl_xor(en, 1);
        if (!(lane & 1))
            std4(Ebo + (long)row * CH + c, pk2(en, vB));
    }
}

// ---------------------------------------------------------------------------
DEV void lin_compute(const bf16* abuf, int r0, int n0, int lane, int wave, int Ktot,
                     const bf16* __restrict__ W,
                     const float* __restrict__ bias, bf16* __restrict__ Out)
{
    const int lr = lane & 15, lkE = (lane >> 4) * 8;
    const int c = n0 + wave * 16 + lr;
    const bf16* arow = abuf + (long)lr * APITCH;
    const bf16* wrow = W + (long)c * Ktot;
    const int kofs = Ktot - CH;

    f32x4 acc = {};
    {
        const bf16* wp = wrow + kofs + lkE;
        bf16x8 wv[8];
#pragma unroll
        for (int j = 0; j < 8; ++j) wv[j] = ldfrag(wp + j * 32);
#pragma unroll
        for (int kb = 0; kb < 32; ++kb) {
            const int sl = kb & 7;
            bf16x8 a = *reinterpret_cast<const bf16x8*>(arow + kofs + kb * 32 + lkE);
            acc = MFMA(a, wv[sl], acc);
            if (kb < 24) wv[sl] = ldfrag(wp + (kb + 8) * 32);
        }
    }
    if (Ktot > CH) {
        bf16x8 wv[4];
#pragma unroll
        for (int j = 0; j < 4; ++j) wv[j] = ldfrag(wrow + j * 32 + lkE);
#pragma unroll
        for (int j = 0; j < 4; ++j) {
            bf16x8 a = *reinterpret_cast<const bf16x8*>(arow + j * 32 + lkE);
            acc = MFMA(a, wv[j], acc);
        }
    }

    const float bb = bias[c];
    const int rbase = r0 + (lane >> 4) * 4;
#pragma unroll
    for (int i = 0; i < 4; ++i) {
        float v = acc[i] + bb;
        float vB = __shfl_xor(v, 1);
        if (!(lane & 1))
            std4(Out + (long)(rbase + i) * CD + c, pk2(v, vB));
    }
}

// ---------------------------------------------------------------------------
// Two-head tail (FB path + P side), r18 verbatim.
// ---------------------------------------------------------------------------
template <bool BIG, int MODE>
DEV void phase_tail2(const Prm& p, int t, int mb, int nb, int tid,
                     int lane, int wave, float* Ra, float* Rs,
                     const bf16* __restrict__ A, float* __restrict__ ztmp,
                     const bf16* __restrict__ Wa, const bf16* __restrict__ Wb,
                     const float* __restrict__ ba, const float* __restrict__ bb)
{
    const int lr = lane & 15, lkE = (lane >> 4) * 8;
    f32x4 am = {}, as = {};
    const int k0 = wave * 128;
    bf16x8 av[4], bmv[4], bsv[4];
#pragma unroll
    for (int j = 0; j < 4; ++j) {
        const int k = k0 + j * 32;
        const bf16* ap = A + (long)(mb + lr) * CD + k + lkE;
        av[j]  = BIG ? ldfrag(ap) : ldd16_nw(ap);
        bmv[j] = ldfrag(Wa + (long)(nb + lr) * CD + k + lkE);
        bsv[j] = ldfrag(Wb + (long)(nb + lr) * CD + k + lkE);
    }
    if constexpr (!BIG) vm_wait0();
#pragma unroll
    for (int j = 0; j < 4; ++j) {
        am = MFMA(av[j], bmv[j], am);
        as = MFMA(av[j], bsv[j], as);
    }
    __syncthreads();
#pragma unroll
    for (int i = 0; i < 4; ++i) {
        Ra[(wave * 16 + (lane >> 4) * 4 + i) * 17 + lr] = am[i];
        Rs[(wave * 16 + (lane >> 4) * 4 + i) * 17 + lr] = as[i];
    }
    __syncthreads();
    if (tid < 256) {
        const int trow = tid >> 4, tcol = tid & 15;
        float vm = 0.f, vs = 0.f;
#pragma unroll
        for (int w = 0; w < 8; ++w) {
            vm += Ra[(w * 16 + trow) * 17 + tcol];
            vs += Rs[(w * 16 + trow) * 17 + tcol];
        }
        const int row = mb + trow, col = nb + tcol;
        if constexpr (MODE == 0) {
            float mu = vm + ba[col];
            float lv = softplusf_(vs + bb[col]);
            float e  = p.eps_q[(long)row * CW * CZ + (long)t * CZ + col];
            float z  = mu + expf(0.5f * lv) * e;
            p.out_mu[(long)row * CW * CZ + (long)t * CZ + col] = mu;
            p.out_lv[(long)row * CW * CZ + (long)t * CZ + col] = lv;
            std4(ztmp + (long)row * CZ + col, __float_as_uint(z));
        } else {
            float m  = vm + ba[col];
            float sg = softplusf_(vs + bb[col]);
            float e  = p.eps_p[(long)row * CW * COUT + (long)t * COUT + col];
            p.out_o[(long)row * CW * COUT + (long)t * COUT + col] = m + sg * e;
        }
    }
}

// ---------------------------------------------------------------------------
// Planar flows + LGSSM on a pre-filled z (zl) — shared body.
// ---------------------------------------------------------------------------
DEV void flows_body(const Prm& p, int rowbase, int tid, int t, float* zl, float* ps,
                    bf16* __restrict__ ztlg, bf16* __restrict__ zflow_next)
{
    const int rg = tid >> 8;
    const int sub = tid & 255;
    const int c = sub & 127, half = sub >> 7;
    const int row = rowbase + rg;
    float* zrow = zl + rg * CZ;
    float* pall = ps + rg * 2 * CZ;

#pragma unroll 1
    for (int kf = 0; kf < 3; ++kf) {
        const float* wr = p.Wp + ((long)kf * CZ + c) * CZ + half * 64;
        const float* zh = zrow + half * 64;
        float s = 0.f;
#pragma unroll
        for (int j = 0; j < 64; j += 4) {
            float4 w = *reinterpret_cast<const float4*>(wr + j);
            s += zh[j] * w.x + zh[j + 1] * w.y + zh[j + 2] * w.z + zh[j + 3] * w.w;
        }
        pall[half * CZ + c] = s;
        __syncthreads();
        if (half == 0) {
            float sf = pall[c] + pall[CZ + c] + p.bp[kf * CZ + c];
            zrow[c] += p.up[kf] * tanhf(sf);
        }
        __syncthreads();
    }
    {
        const float* wr = p.Wlg + (long)c * CZ + half * 64;
        const float* zh = zrow + half * 64;
        float s = 0.f;
#pragma unroll
        for (int j = 0; j < 64; j += 4) {
            float4 w = *reinterpret_cast<const float4*>(wr + j);
            s += zh[j] * w.x + zh[j + 1] * w.y + zh[j + 2] * w.z + zh[j + 3] * w.w;
        }
        pall[half * CZ + c] = s;
        __syncthreads();
        if (half == 0) {
            float zt = pall[c] + pall[CZ + c] + p.blg[c];
            float ztB = __shfl_xor(zt, 1);
            if (!(c & 1)) {
                std4(ztlg + (long)row * CZ + c, pk2(zt, ztB));
                std4(zflow_next + (long)row * CZ + c, pk2(zrow[c], zrow[c + 1]));
            }
        }
    }
}

// ---------------------------------------------------------------------------
// BIG-mode fused Q3+Q4: per-2-row heads (redundant) + reparam + flows.
// scratch layout: dv[2][1032] bf16 | res[2][256] f32 | zl[2][128] | ps[2][2][128]
// ---------------------------------------------------------------------------
DEV void qtail_flows(const Prm& p, int lwg, int tid, int t, char* scratch)
{
    bf16*  dv  = (bf16*)scratch;                         // 4128 B
    float* res = (float*)(scratch + 2 * 1032 * 2);       // 2048 B
    float* zl  = res + 512;                              // 1024 B
    float* ps  = zl + 2 * CZ;                            // 2048 B
    const size_t SD = (size_t)CB * CD, SZ = (size_t)CB * CZ;
    const int row0 = lwg * 2;

    // load this WG's 2 dvec rows (cached unique-address; producers barriered)
    if (tid < 256) {
        const int r = tid >> 7, k = (tid & 127) * 8;
        *reinterpret_cast<bf16x8*>(dv + (long)r * 1032 + k) =
            ldfrag(p.dvec_h + (size_t)t * SD + (size_t)(row0 + r) * CD + k);
    }
    __syncthreads();

    // per-lane dot: weight row wr = tid&255 (0-127 mu, 128-255 sig), rb = tid>>8.
    const int wr = tid & 255, rb = tid >> 8;
    const bf16* wrow = (wr < 128) ? (p.Wmu_qb + (long)wr * CD)
                                  : (p.Wsg_qb + (long)(wr - 128) * CD);
    const bf16* drow = dv + (long)rb * 1032;
    float acc = 0.f;
#pragma unroll 4
    for (int k = 0; k < CD; k += 8) {
        bf16x8 w = ldfrag(wrow + k);
        bf16x8 a = *reinterpret_cast<const bf16x8*>(drow + k);
#pragma unroll
        for (int j = 0; j < 8; ++j) acc += (float)a[j] * (float)w[j];
    }
    res[rb * 256 + wr] = acc;
    __syncthreads();

    if (tid < 256) {
        const int r = tid >> 7, col = tid & 127;
        const int row = row0 + r;
        float mu = res[r * 256 + col] + p.bmu_q[col];
        float lv = softplusf_(res[r * 256 + 128 + col] + p.bsig_q[col]);
        float e  = p.eps_q[(size_t)row * CW * CZ + (size_t)t * CZ + col];
        p.out_mu[(size_t)row * CW * CZ + (size_t)t * CZ + col] = mu;
        p.out_lv[(size_t)row * CW * CZ + (size_t)t * CZ + col] = lv;
        zl[r * CZ + col] = mu + expf(0.5f * lv) * e;
    }
    __syncthreads();

    flows_body(p, row0, tid, t, zl, ps,
               p.ztlg_h + (size_t)t * SZ,
               p.zflow_h + (size_t)(t + 1) * SZ);
}

// ---------------------------------------------------------------------------
template <bool BIG>
DEV void run_q(const Prm& p, int lwg, int tid, char* smem)
{
    bf16*  abuf = (bf16*)smem;
    float* Ra   = (float*)(smem + ABUF_BYTES);
    float* Rs   = Ra + REDN;
    float* ZLp  = (float*)(smem + ABUF_BYTES + RED2_BYTES);
    float* PSp  = ZLp + 2 * CZ;
    const int lane = tid & 63, wave = tid >> 6;
    const int g = lwg >> 5, m = lwg & 31;
    const int r0 = (m >> 1) * 16;
    const int n0 = g * 256 + (m & 1) * 128;
    const int nt = g * 32 + (m & 1) * 16;
    const size_t SH = (size_t)CB * CH, SD = (size_t)CB * CD, SZ = (size_t)CB * CZ;
    u32 bk = 0;
#pragma unroll 1
    for (int t = 0; t < CW; ++t) {
        const int eIn  = BIG ? t : (t & 1);
        const int eOut = BIG ? (t + 1) : ((t + 1) & 1);
        const int dT   = BIG ? t : 0;
        const int zT   = BIG ? t : (t & 1);
        const float* ef_i = (t & 1) ? p.e_f1 : p.e_f0;
        float*       ef_o = (t & 1) ? p.e_f0 : p.e_f1;

        stage_act<BIG, 0>(abuf, tid, r0, p.x_b + (long)t * CIN, (long)CW * CIN,
                          CIN, p.e_h + (size_t)eIn * SH, CH);
        gru_compute(abuf, r0, n0, lane, wave, p.Wih_qb, p.Whh_qb,
                    p.bih_q, p.bhh_q, ef_i, ef_o, p.e_h + (size_t)eOut * SH);
        gbar128(p.qbar, lwg, ++bk);

        stage_act<BIG, 1>(abuf, tid, r0, p.zflow_h + (size_t)eIn * SZ, CZ, CZ,
                          p.e_h + (size_t)eOut * SH, CH);
        lin_compute(abuf, r0, n0, lane, wave, CZ + CH, p.Wd_qb, p.bd_q,
                    p.dvec_h + (size_t)dT * SD);
        gbar128(p.qbar, lwg, ++bk);

        if constexpr (BIG) {
            qtail_flows(p, lwg, tid, t, smem + ABUF_BYTES);
        } else {
            phase_tail2<BIG, 0>(p, t, r0, nt, tid, lane, wave, Ra, Rs,
                                p.dvec_h + (size_t)dT * SD, p.ztmp_h + (size_t)dT * SZ,
                                p.Wmu_qb, p.Wsg_qb, p.bmu_q, p.bsig_q);
            gbar128(p.qbar, lwg, ++bk);
            if (t >= 2) {
                if (tid < 128) {
                    while ((int)__hip_atomic_load(&p.pdone[tid * 16], __ATOMIC_RELAXED,
                                                  __HIP_MEMORY_SCOPE_AGENT) < t - 1)
                        __builtin_amdgcn_s_sleep(2);
                }
                __syncthreads();
            }
            {
                const int rg = tid >> 8, sub = tid & 255;
                const int c = sub & 127, half = sub >> 7;
                if (half == 0)
                    ZLp[rg * CZ + c] = __uint_as_float(
                        ldd4(p.ztmp_h + (size_t)dT * SZ + (long)(lwg * 2 + rg) * CZ + c));
                __syncthreads();
            }
            flows_body(p, lwg * 2, tid, t, ZLp, PSp,
                       p.ztlg_h + (size_t)zT * SZ,
                       p.zflow_h + (size_t)eOut * SZ);
        }
        asm volatile("s_waitcnt vmcnt(0)" ::: "memory");
        __syncthreads();
        if (tid == 0)
            __hip_atomic_store(&p.zbar[lwg * 16], (u32)(t + 1),
                               __ATOMIC_RELAXED, __HIP_MEMORY_SCOPE_AGENT);
        __syncthreads();
    }
}

template <bool BIG>
DEV void run_p(const Prm& p, int lwg, int tid, char* smem)
{
    bf16*  abuf = (bf16*)smem;
    float* Ra   = (float*)(smem + ABUF_BYTES);
    float* Rs   = Ra + REDN;
    const int lane = tid & 63, wave = tid >> 6;
    const int g = lwg >> 5, m = lwg & 31;
    const int r0 = (m >> 1) * 16;
    const int n0 = g * 256 + (m & 1) * 128;
    const int nt = g * 32 + (m & 1) * 16;
    const size_t SH = (size_t)CB * CH, SD = (size_t)CB * CD, SZ = (size_t)CB * CZ;
    u32 bk = 0;
#pragma unroll 1
    for (int t = 0; t < CW; ++t) {
        if (tid < 128) {
            while (__hip_atomic_load(&p.zbar[tid * 16], __ATOMIC_RELAXED,
                                     __HIP_MEMORY_SCOPE_AGENT) < (u32)(t + 1))
                __builtin_amdgcn_s_sleep(2);
        }
        __syncthreads();

        const int sIn  = BIG ? t : (t & 1);
        const int sOut = BIG ? (t + 1) : ((t + 1) & 1);
        const int dT   = BIG ? t : 0;
        const int zT   = BIG ? t : (t & 1);
        const float* df_i = (t & 1) ? p.d_f1 : p.d_f0;
        float*       df_o = (t & 1) ? p.d_f0 : p.d_f1;

        stage_act<BIG, 1>(abuf, tid, r0, p.ztlg_h + (size_t)zT * SZ, CZ, CZ,
                          p.d_h + (size_t)sIn * SH, CH);
        gru_compute(abuf, r0, n0, lane, wave, p.Wih_pb, p.Whh_pb,
                    p.bih_p, p.bhh_p, df_i, df_o, p.d_h + (size_t)sOut * SH);
        gbar128(p.pbar, lwg, ++bk);
        if constexpr (!BIG) {
            if (tid == 0)
                __hip_atomic_store(&p.pdone[lwg * 16], (u32)(t + 1),
                                   __ATOMIC_RELAXED, __HIP_MEMORY_SCOPE_AGENT);
        }

        stage_act<BIG, 0>(abuf, tid, r0, nullptr, 0, 0,
                          p.d_h + (size_t)sOut * SH, CH);
        lin_compute(abuf, r0, n0, lane, wave, CH, p.Wd_pb, p.bd_p,
                    p.ddvec_h + (size_t)dT * SD);
        gbar128(p.pbar, lwg, ++bk);

        phase_tail2<BIG, 1>(p, t, r0, nt, tid, lane, wave, Ra, Rs,
                            p.ddvec_h + (size_t)dT * SD, nullptr,
                            p.Wmu_pb, p.Wsg_pb, p.bmu_p, p.bsig_p);
    }
}

// ---------------------------------------------------------------------------
template <bool BIG>
__launch_bounds__(512)
__global__ void mega(Prm p)
{
    extern __shared__ char smem[];
    const int wg = blockIdx.x, tid = threadIdx.x;
    const int gid = wg & 7, m = wg >> 3;
    const bool isQ = gid < 4;
    const int lwg = (isQ ? gid : gid - 4) * 32 + m;

    if (isQ) run_q<BIG>(p, lwg, tid, smem);
    else     run_p<BIG>(p, lwg, tid, smem);
}

// ---------------------------------------------------------------------------
// Host driver
// ---------------------------------------------------------------------------
extern "C" void kernel_launch(void* const* d_in, const int* in_sizes, int n_in,
                              void* d_out, int out_size, void* d_ws, size_t ws_size,
                              hipStream_t stream)
{
    Prm p;
    const float* x      = (const float*)d_in[0];
    p.eps_q  = (const float*)d_in[1];
    p.eps_p  = (const float*)d_in[2];
    const float* Wih_q  = (const float*)d_in[3];
    const float* Whh_q  = (const float*)d_in[4];
    p.bih_q  = (const float*)d_in[5];
    p.bhh_q  = (const float*)d_in[6];
    const float* Wd_q   = (const float*)d_in[7];
    p.bd_q   = (const float*)d_in[8];
    const float* Wmu_q  = (const float*)d_in[9];
    p.bmu_q  = (const float*)d_in[10];
    const float* Wsig_q = (const float*)d_in[11];
    p.bsig_q = (const float*)d_in[12];
    p.Wp     = (const float*)d_in[13];
    p.bp     = (const float*)d_in[14];
    p.up     = (const float*)d_in[15];
    p.Wlg    = (const float*)d_in[16];
    p.blg    = (const float*)d_in[17];
    const float* Wih_p  = (const float*)d_in[18];
    const float* Whh_p  = (const float*)d_in[19];
    p.bih_p  = (const float*)d_in[20];
    p.bhh_p  = (const float*)d_in[21];
    const float* Wd_p   = (const float*)d_in[22];
    p.bd_p   = (const float*)d_in[23];
    const float* Wmu_p  = (const float*)d_in[24];
    p.bmu_p  = (const float*)d_in[25];
    const float* Wsig_p = (const float*)d_in[26];
    p.bsig_p = (const float*)d_in[27];

    p.out_o  = (float*)d_out;
    p.out_mu = p.out_o + (size_t)CB * CW * COUT;
    p.out_lv = p.out_mu + (size_t)CB * CW * CZ;

    const bool BIGM = ws_size >= (size_t)400 * 1024 * 1024;
    const int NS = BIGM ? (CW + 1) : 2;
    const int NT = BIGM ? CW : 1;
    const int NZ = BIGM ? CW : 2;

    char* wp_ = (char*)d_ws;
    auto carve = [&](size_t bytes) -> void* {
        void* q = (void*)wp_;
        wp_ += (bytes + 255) & ~(size_t)255;
        return q;
    };
    p.e_f0 = (float*)carve((size_t)CB * CH * 4);
    p.e_f1 = (float*)carve((size_t)CB * CH * 4);
    p.d_f0 = (float*)carve((size_t)CB * CH * 4);
    p.d_f1 = (float*)carve((size_t)CB * CH * 4);
    p.e_h     = (bf16*)carve((size_t)NS * CB * CH * 2);
    p.d_h     = (bf16*)carve((size_t)NS * CB * CH * 2);
    p.dvec_h  = (bf16*)carve((size_t)NT * CB * CD * 2);
    p.ddvec_h = (bf16*)carve((size_t)NT * CB * CD * 2);
    p.ztmp_h  = (float*)carve((size_t)NT * CB * CZ * 4);
    p.zflow_h = (bf16*)carve((size_t)NS * CB * CZ * 2);
    p.ztlg_h  = (bf16*)carve((size_t)NZ * CB * CZ * 2);
    p.qbar    = (u32*)carve((size_t)128 * 16 * 4);
    p.pbar    = (u32*)carve((size_t)128 * 16 * 4);
    p.zbar    = (u32*)carve((size_t)128 * 16 * 4);
    p.pdone   = (u32*)carve((size_t)128 * 16 * 4);
    bf16* x_b    = (bf16*)carve((size_t)CB * CW * CIN * 2);
    bf16* Wih_qb = (bf16*)carve((size_t)3 * CH * CIN * 2);
    bf16* Whh_qb = (bf16*)carve((size_t)3 * CH * CH * 2);
    bf16* Wd_qb  = (bf16*)carve((size_t)CD * (CZ + CH) * 2);
    bf16* Wmu_qb = (bf16*)carve((size_t)CZ * CD * 2);
    bf16* Wsg_qb = (bf16*)carve((size_t)CZ * CD * 2);
    bf16* Wih_pb = (bf16*)carve((size_t)3 * CH * CZ * 2);
    bf16* Whh_pb = (bf16*)carve((size_t)3 * CH * CH * 2);
    bf16* Wd_pb  = (bf16*)carve((size_t)CD * CH * 2);
    bf16* Wmu_pb = (bf16*)carve((size_t)COUT * CD * 2);
    bf16* Wsg_pb = (bf16*)carve((size_t)COUT * CD * 2);
    p.x_b = x_b;       p.Wih_qb = Wih_qb; p.Whh_qb = Whh_qb;
    p.Wd_qb = Wd_qb;   p.Wmu_qb = Wmu_qb; p.Wsg_qb = Wsg_qb;
    p.Wih_pb = Wih_pb; p.Whh_pb = Whh_pb; p.Wd_pb = Wd_pb;
    p.Wmu_pb = Wmu_pb; p.Wsg_pb = Wsg_pb;

    (void)hipMemsetAsync(p.e_f0, 0, (size_t)CB * CH * 4, stream);
    (void)hipMemsetAsync(p.d_f0, 0, (size_t)CB * CH * 4, stream);
    (void)hipMemsetAsync(p.e_h, 0, (size_t)CB * CH * 2, stream);      // slot 0
    (void)hipMemsetAsync(p.d_h, 0, (size_t)CB * CH * 2, stream);
    (void)hipMemsetAsync(p.zflow_h, 0, (size_t)CB * CZ * 2, stream);  // slot 0
    (void)hipMemsetAsync(p.qbar, 0, (size_t)128 * 16 * 4, stream);
    (void)hipMemsetAsync(p.pbar, 0, (size_t)128 * 16 * 4, stream);
    (void)hipMemsetAsync(p.zbar, 0, (size_t)128 * 16 * 4, stream);
    (void)hipMemsetAsync(p.pdone, 0, (size_t)128 * 16 * 4, stream);

    auto cvt = [&](const float* s, bf16* d, size_t n) {
        k_cvt<<<dim3((unsigned)((n / 4 + 255) / 256)), dim3(256), 0, stream>>>(s, d, (int)n);
    };
    cvt(x,      x_b,    (size_t)CB * CW * CIN);
    cvt(Wih_q,  Wih_qb, (size_t)3 * CH * CIN);
    cvt(Whh_q,  Whh_qb, (size_t)3 * CH * CH);
    cvt(Wd_q,   Wd_qb,  (size_t)CD * (CZ + CH));
    cvt(Wmu_q,  Wmu_qb, (size_t)CZ * CD);
    cvt(Wsig_q, Wsg_qb, (size_t)CZ * CD);
    cvt(Wih_p,  Wih_pb, (size_t)3 * CH * CZ);
    cvt(Whh_p,  Whh_pb, (size_t)3 * CH * CH);
    cvt(Wd_p,   Wd_pb,  (size_t)CD * CH);
    cvt(Wmu_p,  Wmu_pb, (size_t)COUT * CD);
    cvt(Wsig_p, Wsg_pb, (size_t)COUT * CD);

    if (BIGM)
        mega<true><<<dim3(256), dim3(512), SMEM_BYTES, stream>>>(p);
    else
        mega<false><<<dim3(256), dim3(512), SMEM_BYTES, stream>>>(p);
}